// Round 7
// baseline (2157.346 us; speedup 1.0000x reference)
//
#include <hip/hip_runtime.h>

#define B_TOT 8192
#define T_OBS 128
#define T_FUT 64
#define T_ALL 192
#define DIN 5
#define HD 128
#define BT 32          // batch rows per block (two 16-row MFMA A-tiles)
#define ASTR 136       // Abuf / Gr / Gz row stride (bf16 units), 272 B, 16B-aligned
#define GSTR 132       // Gnh / Gni row stride (f32 units), 528 B, 16B-aligned

typedef __attribute__((ext_vector_type(8))) short short8;
typedef __attribute__((ext_vector_type(4))) float f32x4;

__device__ inline short f2bf(float f) {
    unsigned u = __float_as_uint(f);
    u += 0x7FFFu + ((u >> 16) & 1u);   // round-to-nearest-even
    return (short)(u >> 16);
}
__device__ inline float bf2f(short s) {
    return __uint_as_float(((unsigned)(unsigned short)s) << 16);
}
__device__ inline float exp2_(float x) {   // raw v_exp_f32, no OCML guards
    float r; asm("v_exp_f32 %0, %1" : "=v"(r) : "v"(x)); return r;
}
__device__ inline float sigm(float x) {    // rcp(1+2^(-x*log2e)) : 2 VALU + 2 trans
    return __builtin_amdgcn_rcpf(1.f + exp2_(-1.442695041f * x));
}
__device__ inline float tanh_(float x) {   // 1-2*rcp(1+2^(2x*log2e))
    return 1.f - 2.f * __builtin_amdgcn_rcpf(1.f + exp2_(2.885390082f * x));
}

__device__ inline f32x4 MFMA(short8 a, short8 b, f32x4 c) {
    return __builtin_amdgcn_mfma_f32_16x16x32_bf16(a, b, c, 0, 0, 0);
}

__device__ inline short8 load_w8(const float* p) {
    float4 a = *reinterpret_cast<const float4*>(p);
    float4 b = *reinterpret_cast<const float4*>(p + 4);
    short8 r;
    r[0] = f2bf(a.x); r[1] = f2bf(a.y); r[2] = f2bf(a.z); r[3] = f2bf(a.w);
    r[4] = f2bf(b.x); r[5] = f2bf(b.y); r[6] = f2bf(b.z); r[7] = f2bf(b.w);
    return r;
}
__device__ inline short8 load_w5(const float* p) {
    short8 r = (short8)0;
    r[0] = f2bf(p[0]); r[1] = f2bf(p[1]); r[2] = f2bf(p[2]);
    r[3] = f2bf(p[3]); r[4] = f2bf(p[4]);
    return r;
}

// 768 threads = 12 waves = 3 waves/SIMD from ONE block (multi-block
// co-residency proved unreachable without spill in R1-R6).
// Producer wave w: gate g = w>>2 (0=r,1=z,2=n), col-slices {2*(w&3), +1}
// (16 cols each) -> 40 VGPRs of weights/lane (vs 60 before).
// Gates exchanged via LDS (Gr/Gz bf16; Gnh/Gni f32 since n=tanh(gi+r*gh)
// needs both halves). Elementwise: waves 0-7, 8 el/lane, h in f32 regs.
// Head fused on waves 8/9 in the MFMA phase. 2 barriers/step.
__global__ __launch_bounds__(768)
void gru_tracemodel_kernel(const float* __restrict__ obs, const float* __restrict__ target,
                           const float* __restrict__ eWih, const float* __restrict__ eWhh,
                           const float* __restrict__ ebih, const float* __restrict__ ebhh,
                           const float* __restrict__ cWih, const float* __restrict__ cWhh,
                           const float* __restrict__ cbih, const float* __restrict__ cbhh,
                           const float* __restrict__ headW, const float* __restrict__ headb,
                           float* __restrict__ out)
{
    __shared__ __attribute__((aligned(16))) short Abuf[BT][ASTR];      // 8.5 KB (single-buffered)
    __shared__ __attribute__((aligned(16))) short Grs[BT][ASTR];       // 8.5 KB
    __shared__ __attribute__((aligned(16))) short Gzs[BT][ASTR];       // 8.5 KB
    __shared__ __attribute__((aligned(16))) float Gnh[BT][GSTR];       // 16.5 KB
    __shared__ __attribute__((aligned(16))) float Gni[BT][GSTR];       // 16.5 KB
    __shared__ __attribute__((aligned(16))) short Xbuf[T_ALL][BT][8];  // 96 KB

    const int tid  = threadIdx.x;
    const int wave = tid >> 6;          // 0..11
    const int lane = tid & 63;
    const int q    = lane >> 4;         // quad (A/B k-group, C/D row-group)
    const int c    = lane & 15;         // col-in-tile / A row
    const int g    = wave >> 2;         // gate: 0=r 1=z 2=n
    const int s0   = (wave & 3) * 2;    // first of two 16-col slices
    const int b0   = blockIdx.x * BT;

    // h0 = 0
    for (int i = tid; i < BT * ASTR; i += 768) ((short*)Abuf)[i] = 0;

    // stage all x_t as zero-padded bf16 A-rows
    for (int i = tid; i < T_ALL * BT; i += 768) {
        const int t = i % T_ALL;
        const int r = i / T_ALL;
        const float* src;
        if (t < T_OBS)       src = obs    + ((size_t)(b0 + r) * T_OBS + t) * DIN;
        else if (t == T_OBS) src = obs    + ((size_t)(b0 + r) * T_OBS + (T_OBS - 1)) * DIN;
        else                 src = target + ((size_t)(b0 + r) * T_FUT + (t - T_OBS - 1)) * DIN;
        short* dst = &Xbuf[t][r][0];
        #pragma unroll
        for (int j = 0; j < DIN; ++j) dst[j] = f2bf(src[j]);
        dst[5] = 0; dst[6] = 0; dst[7] = 0;
    }

    // ---- weights: this wave's gate, two 16-col slices ----
    short8 W[2][5];        // [slice][ktile]; kt4 = x-tile (q==0 lanes only)
    float  b1[2], b2[2];   // r/z: b1 = bih+bhh; n: b1 = bhh, b2 = bih

    auto load_phase = [&](const float* Wih, const float* Whh,
                          const float* bih, const float* bhh) {
        #pragma unroll
        for (int sl = 0; sl < 2; ++sl) {
            const int n = g * HD + (s0 + sl) * 16 + c;
            #pragma unroll
            for (int kt = 0; kt < 4; ++kt)
                W[sl][kt] = load_w8(Whh + n * HD + kt * 32 + q * 8);
            W[sl][4] = (q == 0) ? load_w5(Wih + n * DIN) : (short8)0;
            if (g < 2) { b1[sl] = bih[n] + bhh[n]; b2[sl] = 0.f; }
            else       { b1[sl] = bhh[n];          b2[sl] = bih[n]; }
        }
    };
    load_phase(eWih, eWhh, ebih, ebhh);

    // head weights in registers on waves 8/9 (tile = wave-8)
    short8 Whd[4];
    float  hb = 0.f;
    if (wave == 8 || wave == 9) {
        #pragma unroll
        for (int kt = 0; kt < 4; ++kt)
            Whd[kt] = (c < DIN) ? load_w8(headW + c * HD + kt * 32 + q * 8) : (short8)0;
        hb = (c < DIN) ? headb[c] : 0.f;
    }

    // elementwise ownership (waves 0-7): one row, 8 consecutive cols
    const int eidx = wave * 64 + lane;
    const int erow = eidx >> 4;           // 0..31
    const int ecb  = (eidx & 15) * 8;     // col base
    float hreg[8];
    #pragma unroll
    for (int j = 0; j < 8; ++j) hreg[j] = 0.f;

    __syncthreads();

    for (int t = 0; t <= T_ALL; ++t) {
        // ---- phase A: A-fragments, gate MFMAs, head ----
        short8 ah[2][4];
        #pragma unroll
        for (int a = 0; a < 2; ++a) {
            const short* ap = &Abuf[a * 16 + c][0];
            #pragma unroll
            for (int kt = 0; kt < 4; ++kt)
                ah[a][kt] = *reinterpret_cast<const short8*>(ap + kt * 32 + q * 8);
        }

        if ((wave == 8 || wave == 9) && t >= T_OBS + 1) {
            const int a = wave - 8;
            const int s = t - (T_OBS + 1);
            f32x4 acc = {hb, hb, hb, hb};
            #pragma unroll
            for (int kt = 0; kt < 4; ++kt)
                acc = MFMA(ah[a][kt], Whd[kt], acc);
            if (c < DIN) {
                #pragma unroll
                for (int r = 0; r < 4; ++r)
                    out[((size_t)(b0 + a * 16 + q * 4 + r) * T_FUT + s) * DIN + c] = acc[r];
            }
        }
        if (t == T_ALL) break;

        if (t == T_OBS) load_phase(cWih, cWhh, cbih, cbhh);

        short8 ax[2] = {(short8)0, (short8)0};
        if (q == 0) {
            #pragma unroll
            for (int a = 0; a < 2; ++a)
                ax[a] = *reinterpret_cast<const short8*>(&Xbuf[t][a * 16 + c][0]);
        }

        if (g < 2) {
            // r or z: one fused acc per (slice, tile); 20 MFMAs
            f32x4 acc[2][2];
            #pragma unroll
            for (int sl = 0; sl < 2; ++sl)
                #pragma unroll
                for (int a = 0; a < 2; ++a) {
                    acc[sl][a] = (f32x4){b1[sl], b1[sl], b1[sl], b1[sl]};
                    #pragma unroll
                    for (int kt = 0; kt < 4; ++kt)
                        acc[sl][a] = MFMA(ah[a][kt], W[sl][kt], acc[sl][a]);
                    acc[sl][a] = MFMA(ax[a], W[sl][4], acc[sl][a]);
                }
            short (*Gx)[ASTR] = (g == 0) ? Grs : Gzs;
            #pragma unroll
            for (int sl = 0; sl < 2; ++sl)
                #pragma unroll
                for (int a = 0; a < 2; ++a)
                    #pragma unroll
                    for (int r = 0; r < 4; ++r)
                        Gx[a * 16 + q * 4 + r][(s0 + sl) * 16 + c] = f2bf(acc[sl][a][r]);
        } else {
            // n: gh (4 MFMAs) and gi (1 MFMA) kept separate, f32 in LDS
            f32x4 aH[2][2], aI[2][2];
            #pragma unroll
            for (int sl = 0; sl < 2; ++sl)
                #pragma unroll
                for (int a = 0; a < 2; ++a) {
                    aH[sl][a] = (f32x4){b1[sl], b1[sl], b1[sl], b1[sl]};
                    #pragma unroll
                    for (int kt = 0; kt < 4; ++kt)
                        aH[sl][a] = MFMA(ah[a][kt], W[sl][kt], aH[sl][a]);
                    aI[sl][a] = (f32x4){b2[sl], b2[sl], b2[sl], b2[sl]};
                    aI[sl][a] = MFMA(ax[a], W[sl][4], aI[sl][a]);
                }
            #pragma unroll
            for (int sl = 0; sl < 2; ++sl)
                #pragma unroll
                for (int a = 0; a < 2; ++a)
                    #pragma unroll
                    for (int r = 0; r < 4; ++r) {
                        Gnh[a * 16 + q * 4 + r][(s0 + sl) * 16 + c] = aH[sl][a][r];
                        Gni[a * 16 + q * 4 + r][(s0 + sl) * 16 + c] = aI[sl][a][r];
                    }
        }

        __syncthreads();   // gates published

        // ---- phase C: elementwise GRU update (waves 0-7) ----
        if (wave < 8) {
            short8 gr = *reinterpret_cast<const short8*>(&Grs[erow][ecb]);
            short8 gz = *reinterpret_cast<const short8*>(&Gzs[erow][ecb]);
            float4 nh0 = *reinterpret_cast<const float4*>(&Gnh[erow][ecb]);
            float4 nh1 = *reinterpret_cast<const float4*>(&Gnh[erow][ecb + 4]);
            float4 ni0 = *reinterpret_cast<const float4*>(&Gni[erow][ecb]);
            float4 ni1 = *reinterpret_cast<const float4*>(&Gni[erow][ecb + 4]);
            float nh[8] = {nh0.x, nh0.y, nh0.z, nh0.w, nh1.x, nh1.y, nh1.z, nh1.w};
            float ni[8] = {ni0.x, ni0.y, ni0.z, ni0.w, ni1.x, ni1.y, ni1.z, ni1.w};
            short8 hv;
            #pragma unroll
            for (int j = 0; j < 8; ++j) {
                float rv = sigm(bf2f(gr[j]));
                float zv = sigm(bf2f(gz[j]));
                float nv = tanh_(ni[j] + rv * nh[j]);
                float hn = nv + zv * (hreg[j] - nv);   // (1-z)n + z h
                hreg[j] = hn;
                hv[j] = f2bf(hn);
            }
            *reinterpret_cast<short8*>(&Abuf[erow][ecb]) = hv;
        }

        __syncthreads();   // h published
    }
}

extern "C" void kernel_launch(void* const* d_in, const int* in_sizes, int n_in,
                              void* d_out, int out_size, void* d_ws, size_t ws_size,
                              hipStream_t stream)
{
    (void)in_sizes; (void)n_in; (void)d_ws; (void)ws_size; (void)out_size;
    gru_tracemodel_kernel<<<dim3(B_TOT / BT), dim3(768), 0, stream>>>(
        (const float*)d_in[0],  (const float*)d_in[1],
        (const float*)d_in[2],  (const float*)d_in[3],
        (const float*)d_in[4],  (const float*)d_in[5],
        (const float*)d_in[6],  (const float*)d_in[7],
        (const float*)d_in[8],  (const float*)d_in[9],
        (const float*)d_in[10], (const float*)d_in[11],
        (float*)d_out);
}